// Round 1
// baseline (765.007 us; speedup 1.0000x reference)
//
#include <hip/hip_runtime.h>
#include <hip/hip_cooperative_groups.h>
#include <math.h>

namespace cg = cooperative_groups;

#define V 50257
#define H 1024
#define NBLK 1024   // fused grid: exactly 4 blocks/CU co-resident on 256 CUs
#define PRE_ROWS 8  // w_out rows prefetched to LDS per block (32 KB)

// ---------------------------------------------------------------------------
// Shared GRU-cell phase: block computes output element i of one GRU layer.
// All 256 threads cover k (t*4..t*4+3); six length-H dots; t==0 does gates.
// ---------------------------------------------------------------------------
__device__ __forceinline__ void gru_phase(
    float4 xv, float4 hv,
    const float* __restrict__ wih, const float* __restrict__ whh,
    const float* __restrict__ bih, const float* __restrict__ bhh,
    const float* __restrict__ hprev,
    int i, int t, int k0, float (*red)[4],
    float* __restrict__ hdst_ws, float* __restrict__ hdst_out) {
    float acc[6];
#pragma unroll
    for (int g = 0; g < 3; ++g) {
        const float4 wi = *(const float4*)(wih + ((size_t)(g * H + i)) * H + k0);
        acc[g] = wi.x * xv.x + wi.y * xv.y + wi.z * xv.z + wi.w * xv.w;
        const float4 wh = *(const float4*)(whh + ((size_t)(g * H + i)) * H + k0);
        acc[3 + g] = wh.x * hv.x + wh.y * hv.y + wh.z * hv.z + wh.w * hv.w;
    }
#pragma unroll
    for (int g = 0; g < 6; ++g)
        for (int off = 32; off > 0; off >>= 1)
            acc[g] += __shfl_down(acc[g], off, 64);
    const int wave = t >> 6, lane = t & 63;
    if (lane == 0) {
#pragma unroll
        for (int g = 0; g < 6; ++g) red[g][wave] = acc[g];
    }
    __syncthreads();
    if (t == 0) {
        float s[6];
#pragma unroll
        for (int g = 0; g < 6; ++g)
            s[g] = red[g][0] + red[g][1] + red[g][2] + red[g][3];
        const float r = 1.0f / (1.0f + expf(-(s[0] + bih[i] + s[3] + bhh[i])));
        const float z = 1.0f / (1.0f + expf(-(s[1] + bih[H + i] + s[4] + bhh[H + i])));
        const float n = tanhf(s[2] + bih[2 * H + i] + r * (s[5] + bhh[2 * H + i]));
        const float h = (1.0f - z) * n + z * hprev[i];
        hdst_ws[i] = h;
        hdst_out[i] = h;
    }
}

// ---------------------------------------------------------------------------
// Fused cooperative kernel: GRU0 (+ async w_out LDS prefetch) -> sync ->
// GRU1 -> sync -> projection (contiguous 49/50-row panel per block, logits
// held in registers) -> sync -> log-softmax finalize (coalesced writes).
// ---------------------------------------------------------------------------
__global__ __launch_bounds__(256, 4) void fused_kernel(
    const int* __restrict__ idx_p, const float* __restrict__ emb,
    const float* __restrict__ hin,
    const float* __restrict__ wih, const float* __restrict__ whh,
    const float* __restrict__ bih, const float* __restrict__ bhh,
    const float* __restrict__ wout, const float* __restrict__ bout,
    float* __restrict__ out, float* __restrict__ ws) {
    const int b = blockIdx.x;    // 0..1023
    const int t = threadIdx.x;   // 0..255
    const int wave = t >> 6, lane = t & 63;
    const int k0 = t * 4;

    float* h0 = ws;              // 1024
    float* Scells = ws + 1024;   // 64
    float* h1 = ws + 1280;       // 1024

    __shared__ float wlds[PRE_ROWS * H];  // 32 KB: prefetched w_out rows, reused in finalize
    __shared__ float red[6][4];
    __shared__ float logS_sh;

    cg::grid_group grid = cg::this_grid();

    // contiguous row panel owned by this block: blocks 0..80 get 50 rows,
    // the rest 49  (81*50 + 943*49 = 50257 = V, exact)
    const int start = 49 * b + (b < 81 ? b : 81);
    const int cnt = 49 + (b < 81 ? 1 : 0);

    if (b == 0 && t < 64) Scells[t] = 0.0f;

    // ---- async prefetch: first PRE_ROWS rows of this block's panel -> LDS.
    // Overlaps with the GRU0 weight loads below (drained by phase-A barrier).
    // wave w stages local rows jj = w and w+4; 4x 1KB global_load_lds per row.
#pragma unroll
    for (int rr = 0; rr < 2; ++rr) {
        const int jj = wave + 4 * rr;
        const float* grow = wout + (size_t)(start + jj) * H + lane * 4;
        float* lbase = &wlds[jj * H];
#pragma unroll
        for (int c = 0; c < 4; ++c) {
            __builtin_amdgcn_global_load_lds(
                (const __attribute__((address_space(1))) void*)(grow + c * 256),
                (__attribute__((address_space(3))) void*)(lbase + c * 256),
                16, 0, 0);
        }
    }

    // ---- phase A: GRU layer 0 (embedding lookup + ReLU input) ----
    {
        const long long idx = (long long)idx_p[0];
        float4 xv = *(const float4*)(emb + (size_t)idx * H + k0);
        xv.x = fmaxf(xv.x, 0.0f); xv.y = fmaxf(xv.y, 0.0f);
        xv.z = fmaxf(xv.z, 0.0f); xv.w = fmaxf(xv.w, 0.0f);
        const float4 hv = *(const float4*)(hin + k0);
        gru_phase(xv, hv, wih, whh, bih, bhh, hin, b, t, k0, red, h0, out + V);
    }
    grid.sync();

    // ---- phase B: GRU layer 1 (input = h0) ----
    {
        const float4 xv = *(const float4*)(h0 + k0);
        const float4 hv = *(const float4*)(hin + H + k0);
        gru_phase(xv, hv, wih + (size_t)3 * H * H, whh + (size_t)3 * H * H,
                  bih + 3 * H, bhh + 3 * H, hin + H, b, t, k0, red, h1, out + V + H);
    }
    grid.sync();

    // ---- phase C: projection. wave w handles local rows jj = w + 4m. ----
    float4 x4[4];
#pragma unroll
    for (int c = 0; c < 4; ++c) x4[c] = *(const float4*)(h1 + c * 256 + lane * 4);

    float lg[13];
    float esum = 0.0f;  // only lane 0's value is meaningful
#pragma unroll
    for (int m = 0; m < 13; ++m) {
        lg[m] = 0.0f;
        const int jj = wave + 4 * m;
        if (jj < cnt) {
            const int v = start + jj;
            float acc = 0.0f;
            if (jj < PRE_ROWS) {
                const float* lrow = &wlds[jj * H + lane * 4];
#pragma unroll
                for (int c = 0; c < 4; ++c) {
                    const float4 w4 = *(const float4*)(lrow + c * 256);
                    acc += w4.x * x4[c].x + w4.y * x4[c].y + w4.z * x4[c].z + w4.w * x4[c].w;
                }
            } else {
                const float* grow = wout + (size_t)v * H + lane * 4;
#pragma unroll
                for (int c = 0; c < 4; ++c) {
                    const float4 w4 = *(const float4*)(grow + c * 256);
                    acc += w4.x * x4[c].x + w4.y * x4[c].y + w4.z * x4[c].z + w4.w * x4[c].w;
                }
            }
#pragma unroll
            for (int off = 32; off > 0; off >>= 1)
                acc += __shfl_down(acc, off, 64);
            if (lane == 0) {
                const float l = acc + bout[v];
                lg[m] = l;           // logit stays in a register across the sync
                esum += expf(l);
            }
        }
    }
    if (lane == 0) atomicAdd(&Scells[b & 63], esum);

    grid.sync();

    // ---- phase D: finalize. Redistribute logits via LDS for coalesced writes.
    if (lane == 0) {
#pragma unroll
        for (int m = 0; m < 13; ++m) {
            const int jj = wave + 4 * m;
            if (jj < cnt) wlds[jj] = lg[m];
        }
    }
    if (t < 64) {
        float s = __hip_atomic_load(&Scells[t], __ATOMIC_RELAXED, __HIP_MEMORY_SCOPE_AGENT);
#pragma unroll
        for (int off = 32; off > 0; off >>= 1)
            s += __shfl_down(s, off, 64);
        if (t == 0) logS_sh = logf(s);
    }
    __syncthreads();
    const float logS = logS_sh;
    if (t < cnt) out[start + t] = wlds[t] - logS;
}

// ===========================================================================
// Fallback path (previous verified 4-kernel pipeline), used only if the
// cooperative launch is rejected at enqueue/capture time.
// ===========================================================================
__global__ __launch_bounds__(256) void gru0_kernel(
    const int* __restrict__ idx_p, const float* __restrict__ emb,
    const float* __restrict__ hin,
    const float* __restrict__ wih, const float* __restrict__ whh,
    const float* __restrict__ bih, const float* __restrict__ bhh,
    float* __restrict__ hout_ws, float* __restrict__ hout_out,
    float* __restrict__ Scells) {
    const int i = blockIdx.x;
    const int t = threadIdx.x;
    const int k0 = t * 4;
    if (i == 0 && t < 64) Scells[t] = 0.0f;
    const long long idx = (long long)idx_p[0];
    float4 xv = *(const float4*)(emb + (size_t)idx * H + k0);
    xv.x = fmaxf(xv.x, 0.0f); xv.y = fmaxf(xv.y, 0.0f);
    xv.z = fmaxf(xv.z, 0.0f); xv.w = fmaxf(xv.w, 0.0f);
    const float4 hv = *(const float4*)(hin + k0);
    __shared__ float red[6][4];
    gru_phase(xv, hv, wih, whh, bih, bhh, hin, i, t, k0, red, hout_ws, hout_out);
}

__global__ __launch_bounds__(256) void gru1_kernel(
    const float* __restrict__ x, const float* __restrict__ hin,
    const float* __restrict__ wih, const float* __restrict__ whh,
    const float* __restrict__ bih, const float* __restrict__ bhh,
    float* __restrict__ hout_ws, float* __restrict__ hout_out) {
    const int i = blockIdx.x;
    const int t = threadIdx.x;
    const int k0 = t * 4;
    const float4 xv = *(const float4*)(x + k0);
    const float4 hv = *(const float4*)(hin + k0);
    __shared__ float red[6][4];
    gru_phase(xv, hv, wih, whh, bih, bhh, hin, i, t, k0, red, hout_ws, hout_out);
}

__global__ __launch_bounds__(256) void proj_kernel(
    const float* __restrict__ x, const float* __restrict__ wout,
    const float* __restrict__ bout, float* __restrict__ logits,
    float* __restrict__ Scells) {
    const int t = threadIdx.x, wave = t >> 6, lane = t & 63;
    const int v = blockIdx.x * 4 + wave;
    float contrib = 0.0f;
    if (v < V) {
        const float* row = wout + (size_t)v * H;
        float acc = 0.0f;
#pragma unroll
        for (int j = 0; j < 4; ++j) {
            const int k = j * 256 + lane * 4;
            const float4 w = *(const float4*)(row + k);
            const float4 xv = *(const float4*)(x + k);
            acc += w.x * xv.x + w.y * xv.y + w.z * xv.z + w.w * xv.w;
        }
        for (int off = 32; off > 0; off >>= 1)
            acc += __shfl_down(acc, off, 64);
        if (lane == 0) {
            const float lg = acc + bout[v];
            logits[v] = lg;
            contrib = expf(lg);
        }
    }
    __shared__ float lsh[4];
    if (lane == 0) lsh[wave] = contrib;
    __syncthreads();
    if (t == 0)
        atomicAdd(&Scells[blockIdx.x & 63], lsh[0] + lsh[1] + lsh[2] + lsh[3]);
}

__global__ __launch_bounds__(256) void finalize_kernel(
    const float* __restrict__ logits, const float* __restrict__ Scells,
    float* __restrict__ out) {
    __shared__ float logS_sh;
    const int t = threadIdx.x;
    if (t < 64) {
        float s = Scells[t];
        for (int off = 32; off > 0; off >>= 1)
            s += __shfl_down(s, off, 64);
        if (t == 0) logS_sh = logf(s);
    }
    __syncthreads();
    const float logS = logS_sh;
    const int v = blockIdx.x * 256 + t;
    if (v < V) out[v] = logits[v] - logS;
}

extern "C" void kernel_launch(void* const* d_in, const int* in_sizes, int n_in,
                              void* d_out, int out_size, void* d_ws, size_t ws_size,
                              hipStream_t stream) {
    const int*   idx    = (const int*)d_in[0];
    const float* hidden = (const float*)d_in[1];
    const float* emb    = (const float*)d_in[2];
    const float* w_ih   = (const float*)d_in[3];
    const float* w_hh   = (const float*)d_in[4];
    const float* b_ih   = (const float*)d_in[5];
    const float* b_hh   = (const float*)d_in[6];
    const float* w_out  = (const float*)d_in[7];
    const float* b_out  = (const float*)d_in[8];
    float* out = (float*)d_out;
    float* ws  = (float*)d_ws;

    // ws layout (floats): h0 @0 (1024), Scells @1024 (64), h1 @1280 (1024),
    // logits @2304 (V, fallback path only)
    float* h0     = ws;
    float* Scells = ws + 1024;
    float* h1     = ws + 1280;
    float* logits = ws + 2304;

    void* args[] = { (void*)&idx, (void*)&emb, (void*)&hidden,
                     (void*)&w_ih, (void*)&w_hh, (void*)&b_ih, (void*)&b_hh,
                     (void*)&w_out, (void*)&b_out, (void*)&out, (void*)&ws };
    hipError_t e = hipLaunchCooperativeKernel((const void*)fused_kernel,
                                              dim3(NBLK), dim3(256),
                                              (void**)args, 0, stream);
    if (e == hipSuccess) return;

    // Fallback: previous verified 4-kernel pipeline.
    hipLaunchKernelGGL(gru0_kernel, dim3(H), dim3(256), 0, stream,
                       idx, emb, hidden, w_ih, w_hh, b_ih, b_hh,
                       h0, out + V, Scells);
    hipLaunchKernelGGL(gru1_kernel, dim3(H), dim3(256), 0, stream,
                       h0, hidden + H,
                       w_ih + (size_t)3 * H * H, w_hh + (size_t)3 * H * H,
                       b_ih + 3 * H, b_hh + 3 * H,
                       h1, out + V + H);
    const int NB = (V + 3) / 4;
    hipLaunchKernelGGL(proj_kernel, dim3(NB), dim3(256), 0, stream,
                       h1, w_out, b_out, logits, Scells);
    hipLaunchKernelGGL(finalize_kernel, dim3((V + 255) / 256), dim3(256), 0, stream,
                       logits, Scells, out);
}

// Round 3
// 417.344 us; speedup vs baseline: 1.8330x; 1.8330x over previous
//
#include <hip/hip_runtime.h>
#include <math.h>

#define V 50257
#define H 1024

// ---------------------------------------------------------------------------
// Dispatch 1: blocks 0..H-1   = full GRU layer-0 cell for element i=b
//             blocks H..2H-1  = layer-1 hidden-side partial for element j=b-H:
//                               gh[g*H+j] = (w_hh[1] @ h_in[1])[g*H+j] + b_hh[1][g*H+j]
// (layer-1 hidden gates depend only on launch-time inputs, so they overlap
//  with layer 0 here instead of serializing inside the gru1 dispatch)
// Block 0 also zeroes the 64 softmax accumulator cells (ws poisoned 0xAA).
// ---------------------------------------------------------------------------
__global__ __launch_bounds__(256) void k1_kernel(
    const int* __restrict__ idx_p, const float* __restrict__ emb,
    const float* __restrict__ hin,
    const float* __restrict__ wih, const float* __restrict__ whh,
    const float* __restrict__ bih, const float* __restrict__ bhh,
    float* __restrict__ h0_ws, float* __restrict__ hout_out,
    float* __restrict__ Scells, float* __restrict__ gh) {
    const int b = blockIdx.x;       // 0..2H-1
    const int t = threadIdx.x;      // 0..255
    const int k0 = t * 4;
    const int wave = t >> 6, lane = t & 63;

    if (b == 0 && t < 64) Scells[t] = 0.0f;

    if (b < H) {
        // ---- GRU layer 0, output element i ----
        const int i = b;
        const long long idx = (long long)idx_p[0];   // int64 input, low word
        float4 xv = *(const float4*)(emb + (size_t)idx * H + k0);
        xv.x = fmaxf(xv.x, 0.0f); xv.y = fmaxf(xv.y, 0.0f);
        xv.z = fmaxf(xv.z, 0.0f); xv.w = fmaxf(xv.w, 0.0f);
        const float4 hv = *(const float4*)(hin + k0);

        float acc[6];
#pragma unroll
        for (int g = 0; g < 3; ++g) {
            const float4 wi = *(const float4*)(wih + ((size_t)(g * H + i)) * H + k0);
            acc[g] = wi.x * xv.x + wi.y * xv.y + wi.z * xv.z + wi.w * xv.w;
            const float4 wh = *(const float4*)(whh + ((size_t)(g * H + i)) * H + k0);
            acc[3 + g] = wh.x * hv.x + wh.y * hv.y + wh.z * hv.z + wh.w * hv.w;
        }
#pragma unroll
        for (int g = 0; g < 6; ++g)
            for (int off = 32; off > 0; off >>= 1)
                acc[g] += __shfl_down(acc[g], off, 64);

        __shared__ float red[6][4];
        if (lane == 0) {
#pragma unroll
            for (int g = 0; g < 6; ++g) red[g][wave] = acc[g];
        }
        __syncthreads();
        if (t == 0) {
            float s[6];
#pragma unroll
            for (int g = 0; g < 6; ++g)
                s[g] = red[g][0] + red[g][1] + red[g][2] + red[g][3];
            const float r = 1.0f / (1.0f + expf(-(s[0] + bih[i] + s[3] + bhh[i])));
            const float z = 1.0f / (1.0f + expf(-(s[1] + bih[H + i] + s[4] + bhh[H + i])));
            const float n = tanhf(s[2] + bih[2 * H + i] + r * (s[5] + bhh[2 * H + i]));
            const float h = (1.0f - z) * n + z * hin[i];
            h0_ws[i] = h;
            hout_out[i] = h;
        }
    } else {
        // ---- layer-1 hidden-side partial, element j ----
        const int j = b - H;
        const float4 hv = *(const float4*)(hin + H + k0);   // h_in[1]
        const float* whh1 = whh + (size_t)3 * H * H;

        float acc[3];
#pragma unroll
        for (int g = 0; g < 3; ++g) {
            const float4 wh = *(const float4*)(whh1 + ((size_t)(g * H + j)) * H + k0);
            acc[g] = wh.x * hv.x + wh.y * hv.y + wh.z * hv.z + wh.w * hv.w;
        }
#pragma unroll
        for (int g = 0; g < 3; ++g)
            for (int off = 32; off > 0; off >>= 1)
                acc[g] += __shfl_down(acc[g], off, 64);

        __shared__ float red3[3][4];
        if (lane == 0) {
#pragma unroll
            for (int g = 0; g < 3; ++g) red3[g][wave] = acc[g];
        }
        __syncthreads();
        if (t == 0) {
#pragma unroll
            for (int g = 0; g < 3; ++g) {
                const float s = red3[g][0] + red3[g][1] + red3[g][2] + red3[g][3];
                gh[g * H + j] = s + bhh[3 * H + g * H + j];
            }
        }
    }
}

// ---------------------------------------------------------------------------
// Dispatch 2: GRU layer 1, input-side only (3 dots) + gate math using the
// precomputed hidden-side partial gh.
// ---------------------------------------------------------------------------
__global__ __launch_bounds__(256) void gru1_kernel(
    const float* __restrict__ x, const float* __restrict__ hin1,
    const float* __restrict__ wih1, const float* __restrict__ bih1,
    const float* __restrict__ gh,
    float* __restrict__ h1_ws, float* __restrict__ hout_out) {
    const int i = blockIdx.x;
    const int t = threadIdx.x;
    const int k0 = t * 4;
    const int wave = t >> 6, lane = t & 63;

    const float4 xv = *(const float4*)(x + k0);

    float acc[3];
#pragma unroll
    for (int g = 0; g < 3; ++g) {
        const float4 wi = *(const float4*)(wih1 + ((size_t)(g * H + i)) * H + k0);
        acc[g] = wi.x * xv.x + wi.y * xv.y + wi.z * xv.z + wi.w * xv.w;
    }
#pragma unroll
    for (int g = 0; g < 3; ++g)
        for (int off = 32; off > 0; off >>= 1)
            acc[g] += __shfl_down(acc[g], off, 64);

    __shared__ float red[3][4];
    if (lane == 0) {
#pragma unroll
        for (int g = 0; g < 3; ++g) red[g][wave] = acc[g];
    }
    __syncthreads();

    if (t == 0) {
        float s[3];
#pragma unroll
        for (int g = 0; g < 3; ++g)
            s[g] = red[g][0] + red[g][1] + red[g][2] + red[g][3];
        const float r = 1.0f / (1.0f + expf(-(s[0] + bih1[i] + gh[i])));
        const float z = 1.0f / (1.0f + expf(-(s[1] + bih1[H + i] + gh[H + i])));
        const float n = tanhf(s[2] + bih1[2 * H + i] + r * gh[2 * H + i]);
        const float h = (1.0f - z) * n + z * hin1[i];
        h1_ws[i] = h;
        hout_out[i] = h;
    }
}

// ---------------------------------------------------------------------------
// Projection GEMV: one wave per vocab row (4 rows/block), coalesced float4
// loads. No max-subtraction (logits are O(5), fp32-safe); per-block sum of
// exp(logit) accumulated into 64 striped global cells (one atomic per block).
// ---------------------------------------------------------------------------
__global__ __launch_bounds__(256) void proj_kernel(
    const float* __restrict__ x, const float* __restrict__ wout,
    const float* __restrict__ bout, float* __restrict__ logits,
    float* __restrict__ Scells) {
    const int t = threadIdx.x, wave = t >> 6, lane = t & 63;
    const int v = blockIdx.x * 4 + wave;

    float contrib = 0.0f;
    if (v < V) {
        const float* row = wout + (size_t)v * H;
        float acc = 0.0f;
#pragma unroll
        for (int j = 0; j < 4; ++j) {
            const int k = j * 256 + lane * 4;
            const float4 w = *(const float4*)(row + k);
            const float4 xv = *(const float4*)(x + k);
            acc += w.x * xv.x + w.y * xv.y + w.z * xv.z + w.w * xv.w;
        }
        for (int off = 32; off > 0; off >>= 1)
            acc += __shfl_down(acc, off, 64);
        if (lane == 0) {
            const float lg = acc + bout[v];
            logits[v] = lg;
            contrib = expf(lg);
        }
    }

    __shared__ float lsh[4];
    if (lane == 0) lsh[wave] = contrib;
    __syncthreads();
    if (t == 0)
        atomicAdd(&Scells[blockIdx.x & 63], lsh[0] + lsh[1] + lsh[2] + lsh[3]);
}

// ---------------------------------------------------------------------------
// Finalize: each block redundantly reduces the 64 S cells (512 B, L2-hot),
// then writes out = logit - log(S).
// ---------------------------------------------------------------------------
__global__ __launch_bounds__(256) void finalize_kernel(
    const float* __restrict__ logits, const float* __restrict__ Scells,
    float* __restrict__ out) {
    __shared__ float logS_sh;
    const int t = threadIdx.x;
    if (t < 64) {
        float s = Scells[t];
        for (int off = 32; off > 0; off >>= 1)
            s += __shfl_down(s, off, 64);
        if (t == 0) logS_sh = logf(s);
    }
    __syncthreads();
    const float logS = logS_sh;
    const int v = blockIdx.x * 256 + t;
    if (v < V) out[v] = logits[v] - logS;
}

extern "C" void kernel_launch(void* const* d_in, const int* in_sizes, int n_in,
                              void* d_out, int out_size, void* d_ws, size_t ws_size,
                              hipStream_t stream) {
    const int*   idx    = (const int*)d_in[0];
    const float* hidden = (const float*)d_in[1];
    const float* emb    = (const float*)d_in[2];
    const float* w_ih   = (const float*)d_in[3];
    const float* w_hh   = (const float*)d_in[4];
    const float* b_ih   = (const float*)d_in[5];
    const float* b_hh   = (const float*)d_in[6];
    const float* w_out  = (const float*)d_in[7];
    const float* b_out  = (const float*)d_in[8];
    float* out = (float*)d_out;
    float* ws  = (float*)d_ws;

    // ws layout (floats)
    float* h0     = ws;            // 1024
    float* Scells = ws + 1024;     // 64
    float* h1     = ws + 1280;     // 1024
    float* logits = ws + 2304;     // V (ends at 52561)
    float* gh     = ws + 52576;    // 3*H layer-1 hidden-side gates (ends 55648)

    // dispatch 1: GRU0 (blocks 0..1023) + layer-1 hidden partial (1024..2047)
    hipLaunchKernelGGL(k1_kernel, dim3(2 * H), dim3(256), 0, stream,
                       idx, emb, hidden, w_ih, w_hh, b_ih, b_hh,
                       h0, out + V, Scells, gh);

    // dispatch 2: GRU1 input-side + gates
    hipLaunchKernelGGL(gru1_kernel, dim3(H), dim3(256), 0, stream,
                       h0, hidden + H,
                       w_ih + (size_t)3 * H * H, b_ih + 3 * H, gh,
                       h1, out + V + H);

    // dispatch 3: projection GEMV
    const int NB = (V + 3) / 4;  // 12565
    hipLaunchKernelGGL(proj_kernel, dim3(NB), dim3(256), 0, stream,
                       h1, w_out, b_out, logits, Scells);

    // dispatch 4: log-softmax finalize
    hipLaunchKernelGGL(finalize_kernel, dim3((V + 255) / 256), dim3(256), 0, stream,
                       logits, Scells, out);
}